// Round 7
// baseline (241.080 us; speedup 1.0000x reference)
//
#include <hip/hip_runtime.h>
#include <hip/hip_bf16.h>

typedef float f4 __attribute__((ext_vector_type(4)));
typedef float f32x4 __attribute__((ext_vector_type(4)));
typedef short s8v __attribute__((ext_vector_type(8)));
typedef unsigned short u16x8 __attribute__((ext_vector_type(8)));

#define BN_EPS   1e-5f
#define PCEN_EPS 1e-6f

// ---- workspace byte layout (all offsets 16B-aligned) ----
#define POOL1_OFF   0UL
#define POOL1_BYTES (2048UL*25088)                 // bf16 [b][h2][y28][x28][c8]
#define WBF_OFF     (POOL1_OFF + POOL1_BYTES)
#define WBF_BYTES   (50UL*2*32*8*2)                // conv2 W bf16: 51200 B
#define WFC1_OFF    (WBF_OFF + WBF_BYTES)
#define WFC1_BYTES  (208UL*3840*2)                 // fc1 W bf16 padded
#define W1EX_OFF    (WFC1_OFF + WFC1_BYTES)
#define W1EX_BYTES  (8UL*16*136*2)                 // conv1 r-shifted W bf16
#define POOL2_OFF   (W1EX_OFF + W1EX_BYTES)
#define POOL2_BYTES (2048UL*3840*2)                // bf16 [b][3840] (K-padded)
#define PART_OFF    (POOL2_OFF + POOL2_BYTES)
#define PART_BYTES  (8UL*2048*208*4)               // fp32 [ks8][b][208]

static __device__ inline ushort f2bu(float v) {
    __hip_bfloat16 h = __float2bfloat16(v);
    return *(ushort*)&h;
}

// ---------------------------------------------------------------------------
// K_wprep_all: all three weight transforms in ONE dispatch (saves launch gaps)
//   i < 17408:  conv1 -> w1ex[r8][n16][k136]
//   i < 25600:  conv2 -> wbf[tap50][h2][co32][c8]
//   i < 798720: fc1   -> wfc1b[208][3840]
// ---------------------------------------------------------------------------
__global__ __launch_bounds__(256) void k_wprep_all(
    const float* __restrict__ w1, const float* __restrict__ w2,
    const float* __restrict__ wfc1,
    __hip_bfloat16* __restrict__ w1ex, __hip_bfloat16* __restrict__ wbf,
    __hip_bfloat16* __restrict__ wfc1b)
{
    int i = blockIdx.x*256 + threadIdx.x;
    if (i < 8*16*136) {
        int r = i / 2176, rem = i - r*2176;
        int n = rem / 136, k = rem - n*136;
        float v = 0.f;
        if (k < 128) {
            int ky = k >> 4, kx = (k & 15) - r;
            if (ky < 7 && kx >= 0 && kx <= 6 && n < 15)
                v = w1[n*49 + ky*7 + kx];
        }
        w1ex[i] = __float2bfloat16(v);
    }
    if (i < 25600) {
        int c8 = i & 7, co = (i >> 3) & 31, h = (i >> 8) & 1, tap = i >> 9;
        int ci = h*8 + c8;
        float v = 0.f;
        if (tap < 49 && ci < 15 && co < 30)
            v = w2[((co*15 + ci)*7 + tap/7)*7 + (tap%7)];
        wbf[i] = __float2bfloat16(v);
    }
    if (i < 208*3840) {
        int n = i / 3840, k = i - n*3840;
        float v = (n < 200 && k < 3630) ? wfc1[(size_t)n*3630 + k] : 0.f;
        wfc1b[i] = __float2bfloat16(v);
    }
}

// ---------------------------------------------------------------------------
// K1: PCEN (parallel segmented scan, all 256 threads) + conv1 via MFMA
// (r-shift trick) + BN + ReLU + 2x2 pool.  block = 1 image (2048 x 256).
// ---------------------------------------------------------------------------
__global__ __launch_bounds__(256) void k_pcen_conv1(
    const float* __restrict__ x,
    const float* __restrict__ log_s, const float* __restrict__ log_alpha,
    const float* __restrict__ log_delta, const float* __restrict__ log_r,
    const ushort* __restrict__ w1ex, const float* __restrict__ cb1,
    const float* __restrict__ g1, const float* __restrict__ be1,
    const float* __restrict__ mu1, const float* __restrict__ va1,
    __hip_bfloat16* __restrict__ pool1)
{
    __shared__ ushort img_s[64*72 + 520];  // bf16 image, stride 72 (+OOB pad)

    const int tid = threadIdx.x;
    const int b = blockIdx.x;
    const int l   = tid & 63;
    const int wv  = tid >> 6;

    // ---- phase A: direct global load of 16 x's + parallel PCEN ----
    const int hrow = tid >> 2, jseg = tid & 3;
    float xs[16];
    {
        const f4* xr = (const f4*)(x + (size_t)b*4096 + hrow*64 + jseg*16);
        f4 v0 = xr[0], v1 = xr[1], v2 = xr[2], v3 = xr[3];
        *(f4*)&xs[0]  = v0; *(f4*)&xs[4]  = v1;
        *(f4*)&xs[8]  = v2; *(f4*)&xs[12] = v3;
    }
    const float s     = __expf(log_s[0]);
    const float alpha = __expf(log_alpha[0]);
    const float delta = __expf(log_delta[0]);
    const float r     = __expf(log_r[0]);
    const float dr    = __expf(r * __logf(delta));
    const float om    = 1.f - s;

    float m = 0.f;
    #pragma unroll
    for (int i = 0; i < 16; ++i) m = om*m + s*xs[i];

    float A16 = om; A16 *= A16; A16 *= A16; A16 *= A16; A16 *= A16;
    float A32 = A16 * A16;

    float v = m;
    float p = __shfl_up(v, 1, 4); v += (jseg >= 1) ? A16*p : 0.f;
    p = __shfl_up(v, 2, 4);       v += (jseg >= 2) ? A32*p : 0.f;
    p = __shfl_up(v, 1, 4);
    float m_in = (jseg >= 1) ? p : 0.f;

    ushort outp[16];
    m = m_in;
    #pragma unroll
    for (int i = 0; i < 16; ++i) {
        m = om*m + s*xs[i];
        float t = xs[i] * __expf(-alpha * __logf(m + PCEN_EPS)) + delta;
        outp[i] = f2bu(__expf(r * __logf(t)) - dr);
    }
    *(u16x8*)&img_s[hrow*72 + jseg*16]     = *(u16x8*)&outp[0];
    *(u16x8*)&img_s[hrow*72 + jseg*16 + 8] = *(u16x8*)&outp[8];

    // ---- weights: global (L2) -> registers; pool1 pad plane zero-fill ----
    const int n16 = l & 15;
    const int Q4  = l >> 4;
    s8v Bf[2][4];
    #pragma unroll
    for (int rr = 0; rr < 2; ++rr)
        #pragma unroll
        for (int ss = 0; ss < 4; ++ss)
            Bf[rr][ss] = *(const s8v*)&w1ex[((wv*2 + rr)*16 + n16)*136 + ss*32 + Q4*8];

    __hip_bfloat16* outb = pool1 + (size_t)b * 12544;
    for (int pz = tid; pz < 784; pz += 256)
        outb[(784 + pz)*8 + 7] = __float2bfloat16(0.f);

    __syncthreads();

    // ---- phase B: MFMA conv + fused BN/pool/ReLU ----
    const int ch = n16;
    float An = 0.f, Bn = 0.f;
    if (ch < 15) {
        An = g1[ch] * rsqrtf(va1[ch] + BN_EPS);
        Bn = (cb1[ch] - mu1[ch]) * An + be1[ch];
    }
    const int h8 = ch >> 3, c8 = ch & 7;
    const int rowA = l & 15;

    #pragma unroll 1
    for (int it = 0; it < 28; ++it) {
        int a  = it % 7;
        int y0 = (it / 7) * 16;

        s8v Aa[4];
        #pragma unroll
        for (int ss = 0; ss < 4; ++ss)
            Aa[ss] = *(const s8v*)&img_s[(y0 + rowA + ss*2 + (Q4 >> 1))*72
                                         + a*8 + (Q4 & 1)*8];

        f32x4 ac0 = (f32x4){0.f,0.f,0.f,0.f};
        f32x4 ac1 = (f32x4){0.f,0.f,0.f,0.f};
        #pragma unroll
        for (int ss = 0; ss < 4; ++ss) {
            ac0 = __builtin_amdgcn_mfma_f32_16x16x32_bf16(Aa[ss], Bf[0][ss], ac0, 0, 0, 0);
            ac1 = __builtin_amdgcn_mfma_f32_16x16x32_bf16(Aa[ss], Bf[1][ss], ac1, 0, 0, 0);
        }

        if (ch < 15 && y0 + Q4*4 < 56) {
            int pxo = a*4 + wv;
            int py  = (y0 >> 1) + Q4*2;
            float v0 = ac0[0]*An + Bn, v1 = ac0[1]*An + Bn;
            float v2 = ac1[0]*An + Bn, v3 = ac1[1]*An + Bn;
            float p0 = fmaxf(fmaxf(fmaxf(v0, v1), fmaxf(v2, v3)), 0.f);
            outb[h8*6272 + (py*28 + pxo)*8 + c8] = __float2bfloat16(p0);
            float w0 = ac0[2]*An + Bn, w1v = ac0[3]*An + Bn;
            float w2 = ac1[2]*An + Bn, w3 = ac1[3]*An + Bn;
            float p1 = fmaxf(fmaxf(fmaxf(w0, w1v), fmaxf(w2, w3)), 0.f);
            outb[h8*6272 + ((py+1)*28 + pxo)*8 + c8] = __float2bfloat16(p1);
        }
    }
}

// ---------------------------------------------------------------------------
// K2: conv2 implicit GEMM (mfma 16x16x32 bf16) + BN/ReLU/pool -> bf16 padded
// block = 1 image, 256 threads (4 waves). Wave tile: 8 Mfrag x 2 Nfrag
// (M=128/wave) -> 10 LDS b128 reads per 16 MFMAs (was 6 per 8).
// ---------------------------------------------------------------------------
__global__ __launch_bounds__(256, 2) void k_conv2(
    const ushort* __restrict__ pool1u, const ushort* __restrict__ wbfu,
    const float* __restrict__ cb2, const float* __restrict__ g2,
    const float* __restrict__ be2, const float* __restrict__ mu2,
    const float* __restrict__ va2, __hip_bfloat16* __restrict__ pool2b)
{
    __shared__ ushort img_s[12544];   // [h2][p784][c8]
    __shared__ ushort bs_s[25600];    // [tap50][h2][co32][c8]

    const int tid = threadIdx.x;
    const int b = blockIdx.x;

    {
        const f4* src = (const f4*)(pool1u + (size_t)b * 12544);
        f4* dst = (f4*)img_s;
        for (int i = tid; i < 1568; i += 256) dst[i] = src[i];
        const f4* wsrc = (const f4*)wbfu;
        f4* wdst = (f4*)bs_s;
        for (int i = tid; i < 3200; i += 256) wdst[i] = wsrc[i];
    }

    if (tid < 210)
        pool2b[(size_t)b*3840 + 3630 + tid] = __float2bfloat16(0.f);

    __syncthreads();

    const int l  = tid & 63;
    const int wv = tid >> 6;          // 0..3, wave owns M rows wv*128..+127
    const int n16 = l & 15;
    const int Q4  = l >> 4;
    const int h   = Q4 & 1;
    const int qh  = Q4 >> 1;

    int Abase[8];
    #pragma unroll
    for (int mf = 0; mf < 8; ++mf) {
        int P  = wv*128 + mf*16 + n16;
        int Pc = P < 483 ? P : 483;
        int pr = Pc >> 2, sb = Pc & 3;
        int py = pr / 11, px = pr - py*11;
        int oy = 2*py + (sb >> 1), ox = 2*px + (sb & 1);
        Abase[mf] = (h*784 + oy*28 + ox) * 16;
    }
    const int Bb0 = qh*1024 + h*512 + n16*16;
    const int Bb1 = Bb0 + 256;

    const char* imgc = (const char*)img_s;
    const char* bsc  = (const char*)bs_s;

    f32x4 acc[8][2];
    #pragma unroll
    for (int mf = 0; mf < 8; ++mf)
        #pragma unroll
        for (int nf = 0; nf < 2; ++nf)
            acc[mf][nf] = (f32x4){0.f, 0.f, 0.f, 0.f};

    #pragma unroll 1
    for (int t = 0; t < 25; ++t) {
        const int tap0 = 2*t;
        const int tap1 = (2*t + 1 <= 48) ? 2*t + 1 : 48;
        const int o0 = ((tap0/7)*28 + tap0%7) * 16;
        const int o1 = ((tap1/7)*28 + tap1%7) * 16;
        const int offA = qh ? o1 : o0;

        s8v bf[2];
        bf[0] = *(const s8v*)(bsc + (Bb0 + t*2048));
        bf[1] = *(const s8v*)(bsc + (Bb1 + t*2048));
        #pragma unroll
        for (int mf = 0; mf < 8; ++mf) {
            s8v a = *(const s8v*)(imgc + (Abase[mf] + offA));
            acc[mf][0] = __builtin_amdgcn_mfma_f32_16x16x32_bf16(a, bf[0], acc[mf][0], 0, 0, 0);
            acc[mf][1] = __builtin_amdgcn_mfma_f32_16x16x32_bf16(a, bf[1], acc[mf][1], 0, 0, 0);
        }
    }

    #pragma unroll
    for (int nf = 0; nf < 2; ++nf) {
        int co = nf*16 + n16;
        if (co >= 30) continue;
        float A  = g2[co] * rsqrtf(va2[co] + BN_EPS);
        float Bb = (cb2[co] - mu2[co]) * A + be2[co];
        __hip_bfloat16* outp = pool2b + (size_t)b*3840 + co*121;
        #pragma unroll
        for (int mf = 0; mf < 8; ++mf) {
            int pair = wv*32 + mf*4 + Q4;
            if (pair < 121) {
                f32x4 v = acc[mf][nf];
                float m01 = fmaxf(v[0]*A + Bb, v[1]*A + Bb);
                float m23 = fmaxf(v[2]*A + Bb, v[3]*A + Bb);
                outp[pair] = __float2bfloat16(fmaxf(fmaxf(m01, m23), 0.f));
            }
        }
    }
}

// ---------------------------------------------------------------------------
// K3a: fc1 bf16 MFMA GEMM. C[2048,208] = A[2048,3840] * W[208,3840]^T.
// grid 256 = 32 Mtiles(64) x 8 Ksplits(480). block 4 waves; wave = 1 Mfrag x
// 13 Nfrags, fragments direct from global (L2-resident), 15 K-steps of 32.
// ---------------------------------------------------------------------------
__global__ __launch_bounds__(256) void k_fc1(
    const ushort* __restrict__ Ab, const ushort* __restrict__ Wb,
    float* __restrict__ part)
{
    const int tid = threadIdx.x;
    const int bid = blockIdx.x;
    const int ks = bid & 7, mt = bid >> 3;
    const int m0 = mt * 64;
    const int k0 = ks * 480;
    const int wv = tid >> 6, l = tid & 63;
    const int n16 = l & 15, Q4 = l >> 4;

    const ushort* Arow = Ab + (size_t)(m0 + wv*16 + n16) * 3840 + k0 + Q4*8;
    const ushort* Wrow = Wb + (size_t)n16 * 3840 + k0 + Q4*8;

    f32x4 acc[13];
    #pragma unroll
    for (int nf = 0; nf < 13; ++nf) acc[nf] = (f32x4){0.f,0.f,0.f,0.f};

    #pragma unroll 1
    for (int t = 0; t < 15; ++t) {
        s8v a = *(const s8v*)(Arow + t*32);
        s8v bf[13];
        #pragma unroll
        for (int nf = 0; nf < 13; ++nf)
            bf[nf] = *(const s8v*)(Wrow + (size_t)nf*16*3840 + t*32);
        #pragma unroll
        for (int nf = 0; nf < 13; ++nf)
            acc[nf] = __builtin_amdgcn_mfma_f32_16x16x32_bf16(a, bf[nf], acc[nf], 0, 0, 0);
    }

    float* dst = part + ((size_t)ks*2048 + m0 + wv*16 + Q4*4) * 208 + n16;
    #pragma unroll
    for (int nf = 0; nf < 13; ++nf)
        #pragma unroll
        for (int r = 0; r < 4; ++r)
            dst[(size_t)r*208 + nf*16] = acc[nf][r];
}

// ---------------------------------------------------------------------------
// K3b: sum 8 partials + bias + ReLU, fc2 + bias + sigmoid -> float32
// ---------------------------------------------------------------------------
__global__ __launch_bounds__(256) void k_fc2(
    const float* __restrict__ part, const float* __restrict__ fb1,
    const float* __restrict__ W2, const float* __restrict__ fb2,
    float* __restrict__ out)
{
    int b = blockIdx.x * 4 + (threadIdx.x >> 6);
    int l = threadIdx.x & 63;
    float a0 = 0.f, a1 = 0.f;
    #pragma unroll
    for (int j = 0; j < 4; ++j) {
        int n = l + j*64;
        if (n < 200) {
            float v = fb1[n];
            #pragma unroll
            for (int ks = 0; ks < 8; ++ks)
                v += part[((size_t)ks*2048 + b)*208 + n];
            v = fmaxf(v, 0.f);
            a0 += v * W2[n];
            a1 += v * W2[200 + n];
        }
    }
    #pragma unroll
    for (int m = 32; m >= 1; m >>= 1) {
        a0 += __shfl_xor(a0, m);
        a1 += __shfl_xor(a1, m);
    }
    if (l == 0) {
        float z0 = a0 + fb2[0], z1 = a1 + fb2[1];
        out[b*2 + 0] = 1.f / (1.f + expf(-z0));
        out[b*2 + 1] = 1.f / (1.f + expf(-z1));
    }
}

// ---------------------------------------------------------------------------
extern "C" void kernel_launch(void* const* d_in, const int* in_sizes, int n_in,
                              void* d_out, int out_size, void* d_ws, size_t ws_size,
                              hipStream_t stream)
{
    const float* x         = (const float*)d_in[0];
    const float* log_s     = (const float*)d_in[1];
    const float* log_alpha = (const float*)d_in[2];
    const float* log_delta = (const float*)d_in[3];
    const float* log_r     = (const float*)d_in[4];
    const float* conv1_w   = (const float*)d_in[5];
    const float* conv1_b   = (const float*)d_in[6];
    const float* bn1_g     = (const float*)d_in[7];
    const float* bn1_b     = (const float*)d_in[8];
    const float* bn1_m     = (const float*)d_in[9];
    const float* bn1_v     = (const float*)d_in[10];
    const float* conv2_w   = (const float*)d_in[11];
    const float* conv2_b   = (const float*)d_in[12];
    const float* bn2_g     = (const float*)d_in[13];
    const float* bn2_b     = (const float*)d_in[14];
    const float* bn2_m     = (const float*)d_in[15];
    const float* bn2_v     = (const float*)d_in[16];
    const float* fc1_w     = (const float*)d_in[17];
    const float* fc1_b     = (const float*)d_in[18];
    const float* fc2_w     = (const float*)d_in[19];
    const float* fc2_b     = (const float*)d_in[20];

    char* wsb = (char*)d_ws;
    __hip_bfloat16* pool1  = (__hip_bfloat16*)(wsb + POOL1_OFF);
    __hip_bfloat16* wbf    = (__hip_bfloat16*)(wsb + WBF_OFF);
    __hip_bfloat16* wfc1b  = (__hip_bfloat16*)(wsb + WFC1_OFF);
    __hip_bfloat16* w1ex   = (__hip_bfloat16*)(wsb + W1EX_OFF);
    __hip_bfloat16* pool2b = (__hip_bfloat16*)(wsb + POOL2_OFF);
    float* part            = (float*)(wsb + PART_OFF);

    k_wprep_all<<<3120, 256, 0, stream>>>(conv1_w, conv2_w, fc1_w, w1ex, wbf, wfc1b);
    k_pcen_conv1<<<2048, 256, 0, stream>>>(x, log_s, log_alpha, log_delta, log_r,
                                           (const ushort*)w1ex, conv1_b,
                                           bn1_g, bn1_b, bn1_m, bn1_v, pool1);
    k_conv2<<<2048, 256, 0, stream>>>((const ushort*)pool1, (const ushort*)wbf,
                                      conv2_b, bn2_g, bn2_b, bn2_m, bn2_v, pool2b);
    k_fc1<<<256, 256, 0, stream>>>((const ushort*)pool2b, (const ushort*)wfc1b, part);
    k_fc2<<<512, 256, 0, stream>>>(part, fc1_b, fc2_w, fc2_b, (float*)d_out);
}

// Round 8
// 231.369 us; speedup vs baseline: 1.0420x; 1.0420x over previous
//
#include <hip/hip_runtime.h>
#include <hip/hip_bf16.h>

typedef float f4 __attribute__((ext_vector_type(4)));
typedef float f32x4 __attribute__((ext_vector_type(4)));
typedef float f32x16 __attribute__((ext_vector_type(16)));
typedef short s8v __attribute__((ext_vector_type(8)));
typedef unsigned short u16x8 __attribute__((ext_vector_type(8)));

#define BN_EPS   1e-5f
#define PCEN_EPS 1e-6f

// ---- workspace byte layout (all offsets 16B-aligned) ----
// pool1: bf16 [b][h2][y28][x29][c8]  (x padded to 29 for LDS bank rotation)
#define POOL1_OFF   0UL
#define POOL1_IMG   25984UL                        // 2*28*29*8 ushorts * 2B
#define POOL1_BYTES (2048UL*POOL1_IMG)
#define WBF_OFF     (POOL1_OFF + POOL1_BYTES)
#define WBF_BYTES   (49UL*32*16*2)                 // conv2 W bf16 [tap][co32][k16]
#define WFC1_OFF    (WBF_OFF + 50176UL)
#define WFC1_BYTES  (208UL*3840*2)                 // fc1 W bf16 padded
#define W1EX_OFF    (WFC1_OFF + WFC1_BYTES)
#define W1EX_BYTES  (8UL*16*136*2)                 // conv1 r-shifted W bf16
#define POOL2_OFF   (W1EX_OFF + W1EX_BYTES)
#define POOL2_BYTES (2048UL*3840*2)                // bf16 [b][3840] (K-padded)
#define PART_OFF    (POOL2_OFF + POOL2_BYTES)
#define PART_BYTES  (8UL*2048*208*4)               // fp32 [ks8][b][208]

static __device__ inline ushort f2bu(float v) {
    __hip_bfloat16 h = __float2bfloat16(v);
    return *(ushort*)&h;
}

// ---------------------------------------------------------------------------
// K_wprep_all: all three weight transforms in ONE dispatch
//   conv1 -> w1ex[r8][n16][k136]
//   conv2 -> wbf[tap49][co32][k16]   (k = ci, 15 padded to 16)
//   fc1   -> wfc1b[208][3840]
// ---------------------------------------------------------------------------
__global__ __launch_bounds__(256) void k_wprep_all(
    const float* __restrict__ w1, const float* __restrict__ w2,
    const float* __restrict__ wfc1,
    __hip_bfloat16* __restrict__ w1ex, __hip_bfloat16* __restrict__ wbf,
    __hip_bfloat16* __restrict__ wfc1b)
{
    int i = blockIdx.x*256 + threadIdx.x;
    if (i < 8*16*136) {
        int r = i / 2176, rem = i - r*2176;
        int n = rem / 136, k = rem - n*136;
        float v = 0.f;
        if (k < 128) {
            int ky = k >> 4, kx = (k & 15) - r;
            if (ky < 7 && kx >= 0 && kx <= 6 && n < 15)
                v = w1[n*49 + ky*7 + kx];
        }
        w1ex[i] = __float2bfloat16(v);
    }
    if (i < 49*32*16) {
        int k = i & 15, co = (i >> 4) & 31, tap = i >> 9;
        float v = 0.f;
        if (k < 15 && co < 30)
            v = w2[((co*15 + k)*7 + tap/7)*7 + (tap%7)];
        wbf[i] = __float2bfloat16(v);
    }
    if (i < 208*3840) {
        int n = i / 3840, k = i - n*3840;
        float v = (n < 200 && k < 3630) ? wfc1[(size_t)n*3630 + k] : 0.f;
        wfc1b[i] = __float2bfloat16(v);
    }
}

// ---------------------------------------------------------------------------
// K1: PCEN (parallel segmented scan, all 256 threads) + conv1 via MFMA
// (r-shift trick) + BN + ReLU + 2x2 pool -> pool1 [b][h2][y28][x29][c8]
// ---------------------------------------------------------------------------
__global__ __launch_bounds__(256) void k_pcen_conv1(
    const float* __restrict__ x,
    const float* __restrict__ log_s, const float* __restrict__ log_alpha,
    const float* __restrict__ log_delta, const float* __restrict__ log_r,
    const ushort* __restrict__ w1ex, const float* __restrict__ cb1,
    const float* __restrict__ g1, const float* __restrict__ be1,
    const float* __restrict__ mu1, const float* __restrict__ va1,
    __hip_bfloat16* __restrict__ pool1)
{
    __shared__ ushort img_s[64*72 + 520];  // bf16 image, stride 72 (+OOB pad)

    const int tid = threadIdx.x;
    const int b = blockIdx.x;
    const int l   = tid & 63;
    const int wv  = tid >> 6;

    // ---- phase A: direct global load of 16 x's + parallel PCEN ----
    const int hrow = tid >> 2, jseg = tid & 3;
    float xs[16];
    {
        const f4* xr = (const f4*)(x + (size_t)b*4096 + hrow*64 + jseg*16);
        f4 v0 = xr[0], v1 = xr[1], v2 = xr[2], v3 = xr[3];
        *(f4*)&xs[0]  = v0; *(f4*)&xs[4]  = v1;
        *(f4*)&xs[8]  = v2; *(f4*)&xs[12] = v3;
    }
    const float s     = __expf(log_s[0]);
    const float alpha = __expf(log_alpha[0]);
    const float delta = __expf(log_delta[0]);
    const float r     = __expf(log_r[0]);
    const float dr    = __expf(r * __logf(delta));
    const float om    = 1.f - s;

    float m = 0.f;
    #pragma unroll
    for (int i = 0; i < 16; ++i) m = om*m + s*xs[i];

    float A16 = om; A16 *= A16; A16 *= A16; A16 *= A16; A16 *= A16;
    float A32 = A16 * A16;

    float v = m;
    float p = __shfl_up(v, 1, 4); v += (jseg >= 1) ? A16*p : 0.f;
    p = __shfl_up(v, 2, 4);       v += (jseg >= 2) ? A32*p : 0.f;
    p = __shfl_up(v, 1, 4);
    float m_in = (jseg >= 1) ? p : 0.f;

    ushort outp[16];
    m = m_in;
    #pragma unroll
    for (int i = 0; i < 16; ++i) {
        m = om*m + s*xs[i];
        float t = xs[i] * __expf(-alpha * __logf(m + PCEN_EPS)) + delta;
        outp[i] = f2bu(__expf(r * __logf(t)) - dr);
    }
    *(u16x8*)&img_s[hrow*72 + jseg*16]     = *(u16x8*)&outp[0];
    *(u16x8*)&img_s[hrow*72 + jseg*16 + 8] = *(u16x8*)&outp[8];

    // ---- weights: global (L2) -> registers; pool1 ci15-pad zero-fill ----
    const int n16 = l & 15;
    const int Q4  = l >> 4;
    s8v Bf[2][4];
    #pragma unroll
    for (int rr = 0; rr < 2; ++rr)
        #pragma unroll
        for (int ss = 0; ss < 4; ++ss)
            Bf[rr][ss] = *(const s8v*)&w1ex[((wv*2 + rr)*16 + n16)*136 + ss*32 + Q4*8];

    __hip_bfloat16* outb = pool1 + (size_t)b * 12992;
    for (int pz = tid; pz < 784; pz += 256) {
        int yy = pz / 28, xx = pz - yy*28;
        outb[6496 + (yy*29 + xx)*8 + 7] = __float2bfloat16(0.f);
    }

    __syncthreads();

    // ---- phase B: MFMA conv + fused BN/pool/ReLU ----
    const int ch = n16;
    float An = 0.f, Bn = 0.f;
    if (ch < 15) {
        An = g1[ch] * rsqrtf(va1[ch] + BN_EPS);
        Bn = (cb1[ch] - mu1[ch]) * An + be1[ch];
    }
    const int h8 = ch >> 3, c8 = ch & 7;
    const int rowA = l & 15;

    #pragma unroll 1
    for (int it = 0; it < 28; ++it) {
        int a  = it % 7;
        int y0 = (it / 7) * 16;

        s8v Aa[4];
        #pragma unroll
        for (int ss = 0; ss < 4; ++ss)
            Aa[ss] = *(const s8v*)&img_s[(y0 + rowA + ss*2 + (Q4 >> 1))*72
                                         + a*8 + (Q4 & 1)*8];

        f32x4 ac0 = (f32x4){0.f,0.f,0.f,0.f};
        f32x4 ac1 = (f32x4){0.f,0.f,0.f,0.f};
        #pragma unroll
        for (int ss = 0; ss < 4; ++ss) {
            ac0 = __builtin_amdgcn_mfma_f32_16x16x32_bf16(Aa[ss], Bf[0][ss], ac0, 0, 0, 0);
            ac1 = __builtin_amdgcn_mfma_f32_16x16x32_bf16(Aa[ss], Bf[1][ss], ac1, 0, 0, 0);
        }

        if (ch < 15 && y0 + Q4*4 < 56) {
            int pxo = a*4 + wv;
            int py  = (y0 >> 1) + Q4*2;
            float v0 = ac0[0]*An + Bn, v1 = ac0[1]*An + Bn;
            float v2 = ac1[0]*An + Bn, v3 = ac1[1]*An + Bn;
            float p0 = fmaxf(fmaxf(fmaxf(v0, v1), fmaxf(v2, v3)), 0.f);
            outb[h8*6496 + (py*29 + pxo)*8 + c8] = __float2bfloat16(p0);
            float w0 = ac0[2]*An + Bn, w1v = ac0[3]*An + Bn;
            float w2 = ac1[2]*An + Bn, w3 = ac1[3]*An + Bn;
            float p1 = fmaxf(fmaxf(fmaxf(w0, w1v), fmaxf(w2, w3)), 0.f);
            outb[h8*6496 + ((py+1)*29 + pxo)*8 + c8] = __float2bfloat16(p1);
        }
    }
}

// ---------------------------------------------------------------------------
// K2 v3: conv2 implicit GEMM via mfma_f32_32x32x16_bf16.
// block = 1 image, 256 threads (4 waves), wave = 4 Mfrags of 32 rows (M=512).
// N=32 covers all 30 co in one B-frag; B read from global (L1/L2-resident).
// LDS = padded bf16 image only (25.4 KB). K-step = 1 tap x 16 ci.
// A[m=lane&31][k=(lane>>5)*8+j]; C/D row=(reg&3)+8*(reg>>2)+4*(lane>>5).
// reg-quad g = one 2x2 pool window -> in-register BN/pool/ReLU.
// ---------------------------------------------------------------------------
__global__ __launch_bounds__(256, 4) void k_conv2(
    const ushort* __restrict__ pool1u, const ushort* __restrict__ wbfu,
    const float* __restrict__ cb2, const float* __restrict__ g2,
    const float* __restrict__ be2, const float* __restrict__ mu2,
    const float* __restrict__ va2, __hip_bfloat16* __restrict__ pool2b)
{
    __shared__ ushort img_s[12992];   // [h2][y28][x29][c8]

    const int tid = threadIdx.x;
    const int b = blockIdx.x;

    {
        const f4* src = (const f4*)(pool1u + (size_t)b * 12992);
        f4* dst = (f4*)img_s;
        for (int i = tid; i < 1624; i += 256) dst[i] = src[i];
    }
    if (tid < 210)
        pool2b[(size_t)b*3840 + 3630 + tid] = __float2bfloat16(0.f);
    __syncthreads();

    const int l   = tid & 63;
    const int wv  = tid >> 6;         // 0..3
    const int n32 = l & 31;           // co / B n-index
    const int h2  = l >> 5;           // k-half (A: h2*8 k-offset; C: +4*h2 row)

    // per-Mfrag A base byte addresses
    int Abase[4];
    #pragma unroll
    for (int mf = 0; mf < 4; ++mf) {
        int P  = (wv*4 + mf)*32 + n32;
        int Pc = P < 483 ? P : 483;
        int pr = Pc >> 2, sb = Pc & 3;
        int py = pr / 11, px = pr - py*11;
        int oy = 2*py + (sb >> 1), ox = 2*px + (sb & 1);
        Abase[mf] = (h2*812 + oy*29 + ox) * 16;
    }
    const ushort* Bt = wbfu + n32*16 + h2*8;
    const char* imgc = (const char*)img_s;

    f32x16 acc[4];
    #pragma unroll
    for (int mf = 0; mf < 4; ++mf)
        #pragma unroll
        for (int q = 0; q < 16; ++q) acc[mf][q] = 0.f;

    #pragma unroll 1
    for (int ty = 0; ty < 7; ++ty) {
        #pragma unroll
        for (int tx = 0; tx < 7; ++tx) {
            const int tap = ty*7 + tx;
            s8v bfr = *(const s8v*)(Bt + tap*512);
            const int offA = (ty*29 + tx)*16;
            #pragma unroll
            for (int mf = 0; mf < 4; ++mf) {
                s8v a = *(const s8v*)(imgc + (Abase[mf] + offA));
                acc[mf] = __builtin_amdgcn_mfma_f32_32x32x16_bf16(a, bfr, acc[mf], 0, 0, 0);
            }
        }
    }

    // epilogue: BN + 2x2 pool + ReLU
    const int co = n32;
    if (co < 30) {
        float A  = g2[co] * rsqrtf(va2[co] + BN_EPS);
        float Bb = (cb2[co] - mu2[co]) * A + be2[co];
        __hip_bfloat16* outp = pool2b + (size_t)b*3840 + co*121;
        #pragma unroll
        for (int mf = 0; mf < 4; ++mf) {
            #pragma unroll
            for (int g = 0; g < 4; ++g) {
                int pair = (wv*4 + mf)*8 + 2*g + h2;
                if (pair < 121) {
                    float v0 = acc[mf][4*g+0]*A + Bb;
                    float v1 = acc[mf][4*g+1]*A + Bb;
                    float v2 = acc[mf][4*g+2]*A + Bb;
                    float v3 = acc[mf][4*g+3]*A + Bb;
                    float pv = fmaxf(fmaxf(fmaxf(v0, v1), fmaxf(v2, v3)), 0.f);
                    outp[pair] = __float2bfloat16(pv);
                }
            }
        }
    }
}

// ---------------------------------------------------------------------------
// K3a: fc1 bf16 MFMA GEMM. C[2048,208] = A[2048,3840] * W[208,3840]^T.
// grid 256 = 32 Mtiles(64) x 8 Ksplits(480). block 4 waves; wave = 1 Mfrag x
// 13 Nfrags, fragments direct from global (L2-resident), 15 K-steps of 32.
// ---------------------------------------------------------------------------
__global__ __launch_bounds__(256) void k_fc1(
    const ushort* __restrict__ Ab, const ushort* __restrict__ Wb,
    float* __restrict__ part)
{
    const int tid = threadIdx.x;
    const int bid = blockIdx.x;
    const int ks = bid & 7, mt = bid >> 3;
    const int m0 = mt * 64;
    const int k0 = ks * 480;
    const int wv = tid >> 6, l = tid & 63;
    const int n16 = l & 15, Q4 = l >> 4;

    const ushort* Arow = Ab + (size_t)(m0 + wv*16 + n16) * 3840 + k0 + Q4*8;
    const ushort* Wrow = Wb + (size_t)n16 * 3840 + k0 + Q4*8;

    f32x4 acc[13];
    #pragma unroll
    for (int nf = 0; nf < 13; ++nf) acc[nf] = (f32x4){0.f,0.f,0.f,0.f};

    #pragma unroll 1
    for (int t = 0; t < 15; ++t) {
        s8v a = *(const s8v*)(Arow + t*32);
        s8v bf[13];
        #pragma unroll
        for (int nf = 0; nf < 13; ++nf)
            bf[nf] = *(const s8v*)(Wrow + (size_t)nf*16*3840 + t*32);
        #pragma unroll
        for (int nf = 0; nf < 13; ++nf)
            acc[nf] = __builtin_amdgcn_mfma_f32_16x16x32_bf16(a, bf[nf], acc[nf], 0, 0, 0);
    }

    float* dst = part + ((size_t)ks*2048 + m0 + wv*16 + Q4*4) * 208 + n16;
    #pragma unroll
    for (int nf = 0; nf < 13; ++nf)
        #pragma unroll
        for (int r = 0; r < 4; ++r)
            dst[(size_t)r*208 + nf*16] = acc[nf][r];
}

// ---------------------------------------------------------------------------
// K3b: sum 8 partials + bias + ReLU, fc2 + bias + sigmoid -> float32
// ---------------------------------------------------------------------------
__global__ __launch_bounds__(256) void k_fc2(
    const float* __restrict__ part, const float* __restrict__ fb1,
    const float* __restrict__ W2, const float* __restrict__ fb2,
    float* __restrict__ out)
{
    int b = blockIdx.x * 4 + (threadIdx.x >> 6);
    int l = threadIdx.x & 63;
    float a0 = 0.f, a1 = 0.f;
    #pragma unroll
    for (int j = 0; j < 4; ++j) {
        int n = l + j*64;
        if (n < 200) {
            float v = fb1[n];
            #pragma unroll
            for (int ks = 0; ks < 8; ++ks)
                v += part[((size_t)ks*2048 + b)*208 + n];
            v = fmaxf(v, 0.f);
            a0 += v * W2[n];
            a1 += v * W2[200 + n];
        }
    }
    #pragma unroll
    for (int m = 32; m >= 1; m >>= 1) {
        a0 += __shfl_xor(a0, m);
        a1 += __shfl_xor(a1, m);
    }
    if (l == 0) {
        float z0 = a0 + fb2[0], z1 = a1 + fb2[1];
        out[b*2 + 0] = 1.f / (1.f + expf(-z0));
        out[b*2 + 1] = 1.f / (1.f + expf(-z1));
    }
}

// ---------------------------------------------------------------------------
extern "C" void kernel_launch(void* const* d_in, const int* in_sizes, int n_in,
                              void* d_out, int out_size, void* d_ws, size_t ws_size,
                              hipStream_t stream)
{
    const float* x         = (const float*)d_in[0];
    const float* log_s     = (const float*)d_in[1];
    const float* log_alpha = (const float*)d_in[2];
    const float* log_delta = (const float*)d_in[3];
    const float* log_r     = (const float*)d_in[4];
    const float* conv1_w   = (const float*)d_in[5];
    const float* conv1_b   = (const float*)d_in[6];
    const float* bn1_g     = (const float*)d_in[7];
    const float* bn1_b     = (const float*)d_in[8];
    const float* bn1_m     = (const float*)d_in[9];
    const float* bn1_v     = (const float*)d_in[10];
    const float* conv2_w   = (const float*)d_in[11];
    const float* conv2_b   = (const float*)d_in[12];
    const float* bn2_g     = (const float*)d_in[13];
    const float* bn2_b     = (const float*)d_in[14];
    const float* bn2_m     = (const float*)d_in[15];
    const float* bn2_v     = (const float*)d_in[16];
    const float* fc1_w     = (const float*)d_in[17];
    const float* fc1_b     = (const float*)d_in[18];
    const float* fc2_w     = (const float*)d_in[19];
    const float* fc2_b     = (const float*)d_in[20];

    char* wsb = (char*)d_ws;
    __hip_bfloat16* pool1  = (__hip_bfloat16*)(wsb + POOL1_OFF);
    __hip_bfloat16* wbf    = (__hip_bfloat16*)(wsb + WBF_OFF);
    __hip_bfloat16* wfc1b  = (__hip_bfloat16*)(wsb + WFC1_OFF);
    __hip_bfloat16* w1ex   = (__hip_bfloat16*)(wsb + W1EX_OFF);
    __hip_bfloat16* pool2b = (__hip_bfloat16*)(wsb + POOL2_OFF);
    float* part            = (float*)(wsb + PART_OFF);

    k_wprep_all<<<3120, 256, 0, stream>>>(conv1_w, conv2_w, fc1_w, w1ex, wbf, wfc1b);
    k_pcen_conv1<<<2048, 256, 0, stream>>>(x, log_s, log_alpha, log_delta, log_r,
                                           (const ushort*)w1ex, conv1_b,
                                           bn1_g, bn1_b, bn1_m, bn1_v, pool1);
    k_conv2<<<2048, 256, 0, stream>>>((const ushort*)pool1, (const ushort*)wbf,
                                      conv2_b, bn2_g, bn2_b, bn2_m, bn2_v, pool2b);
    k_fc1<<<256, 256, 0, stream>>>((const ushort*)pool2b, (const ushort*)wfc1b, part);
    k_fc2<<<512, 256, 0, stream>>>(part, fc1_b, fc2_w, fc2_b, (float*)d_out);
}